// Round 10
// baseline (80.256 us; speedup 1.0000x reference)
//
#include <hip/hip_runtime.h>
#include <hip/hip_bf16.h>

#define BB 4
#define NN 512
#define EE 256
#define HH 8
#define DD 32
#define SCALING 0.17677669529663687f  // 32^-0.5
#define PR 8   // rows per proj block
#define RR 4   // rows per attn block
#define CH (NN / 64)  // m-chunks per wave (lanes cover 64 columns each)

// ---------------------------------------------------------------------------
// Projection, one W per block (blockIdx.y: 0=Q,1=K,2=V).  Q pre-scaled
// [b,n,e]; K transposed Kt[((b*H+h)*D+d)*N+n] (coalesced reads in attn);
// V folded against Wf1/2/3 -> vw[((b*H+h)*3+c)*N+m].  768 blocks.
// ---------------------------------------------------------------------------
__global__ __launch_bounds__(256) void proj_kernel(
    const float* __restrict__ query,
    const float* __restrict__ Wq, const float* __restrict__ bq,
    const float* __restrict__ Wk, const float* __restrict__ bk,
    const float* __restrict__ Wv, const float* __restrict__ bv,
    const float* __restrict__ Wf1, const float* __restrict__ Wf2,
    const float* __restrict__ Wf3,
    float* __restrict__ Q, float* __restrict__ Kt, float* __restrict__ vw)
{
    __shared__ alignas(16) float s[PR][EE];    // 8 KB
    __shared__ alignas(16) float sv[PR][EE];   // 8 KB (V blocks only)
    const int which = blockIdx.y;
    const int row0 = blockIdx.x * PR;
    const int tid = threadIdx.x;               // output column e

    {
        const float4* src = (const float4*)(query + row0 * EE);
        ((float4*)s)[tid]       = src[tid];
        ((float4*)s)[tid + 256] = src[tid + 256];
    }
    __syncthreads();

    const float* W  = (which == 0) ? Wq : (which == 1) ? Wk : Wv;
    const float* bb = (which == 0) ? bq : (which == 1) ? bk : bv;

    float acc[PR];
    #pragma unroll
    for (int r = 0; r < PR; ++r) acc[r] = 0.f;

    const float4* W4 = (const float4*)(W + tid * EE);
    for (int j = 0; j < EE / 4; ++j) {
        const float4 w = W4[j];
        #pragma unroll
        for (int r = 0; r < PR; ++r) {
            const float4 x = *(const float4*)&s[r][4 * j];
            acc[r] += x.x * w.x + x.y * w.y + x.z * w.z + x.w * w.w;
        }
    }
    const float bbv = bb[tid];

    if (which == 0) {
        #pragma unroll
        for (int r = 0; r < PR; ++r)
            Q[(row0 + r) * EE + tid] = (acc[r] + bbv) * SCALING;
    } else if (which == 1) {
        const int h = tid >> 5, d = tid & 31;
        #pragma unroll
        for (int r = 0; r < PR; ++r) {
            const int grow = row0 + r;
            const int b = grow >> 9, n = grow & 511;
            Kt[((size_t)(b * HH + h) * DD + d) * NN + n] = acc[r] + bbv;
        }
    } else {
        #pragma unroll
        for (int r = 0; r < PR; ++r) sv[r][tid] = acc[r] + bbv;
        __syncthreads();
        if (tid < PR * 24) {                   // 192 threads: (r, h, c)
            const int r = tid / 24;
            const int rem = tid % 24;
            const int hh = rem / 3;
            const int c = rem % 3;
            const float* Wf = (c == 0) ? Wf1 : (c == 1) ? Wf2 : Wf3;
            float a = 0.f;
            #pragma unroll
            for (int dd = 0; dd < DD; ++dd)
                a += sv[r][hh * DD + dd] * Wf[hh * DD + dd];
            const int grow = row0 + r;
            const int b = grow >> 9, m = grow & 511;
            vw[((b * HH + hh) * 3 + c) * NN + m] = a;
        }
    }
}

// ---------------------------------------------------------------------------
// Fused attention, wave-per-head: block = (b, 4 rows), wave w = head w,
// lanes sweep m in 8 chunks of 64.
//   P1: per chunk, l = q.k + bias (all K loads independent across chunks ->
//       deep pipelining); e = exp(l) accumulated into per-lane S; e kept
//       packed bf16x2 (16 VGPRs).  Softmax S: ONE wave-local butterfly,
//       no barriers, no LDS.
//   P2: per chunk, A_c[r] += e*rcpS*mask*delta_c*vw_c (delta staged in LDS).
//   P3: butterfly the 12 A values per wave, fold 8 heads via tiny LDS.
// 2 barriers total (sdp stage, final fold).
// ---------------------------------------------------------------------------
__global__ __launch_bounds__(512) void attn_fused_kernel(
    const float* __restrict__ Q, const float* __restrict__ Kt,
    const float* __restrict__ attn_bias, const float* __restrict__ vw,
    const float* __restrict__ delta_pos,
    const int* __restrict__ drop_edge_mask, const int* __restrict__ drop_or_add,
    const float* __restrict__ bf1, const float* __restrict__ bf2,
    const float* __restrict__ bf3, float* __restrict__ out)
{
    const int blk = blockIdx.x;                // 512 blocks
    const int b = blk >> 7;
    const int n0 = (blk & 127) * RR;
    const int tid = threadIdx.x;
    const int ln = tid & 63;
    const int h = __builtin_amdgcn_readfirstlane(tid >> 6);  // wave's head

    __shared__ float sdp[RR * 3 * NN];         // 24 KB staged delta rows
    __shared__ float r3[HH][RR * 3];           // 384 B per-head results

    // coalesced stage of 4 contiguous delta rows (6144 floats, linear copy)
    {
        const float* dpb = delta_pos + (size_t)(b * NN + n0) * NN * 3;
        #pragma unroll
        for (int i = 0; i < RR * 3; ++i)
            sdp[i * 512 + tid] = dpb[i * 512 + tid];
    }

    const float* kp    = Kt + (size_t)(b * HH + h) * DD * NN;
    const float* qb    = Q + (b * NN + n0) * EE + h * DD;    // wave-uniform
    const float* biasb = attn_bias + ((size_t)(b * HH + h) * NN + n0) * NN;

    unsigned int ep[CH][RR / 2];               // bf16x2-packed e, 16 VGPRs
    float S[RR] = {0.f, 0.f, 0.f, 0.f};

    // ---- Phase 1: logits + exp for this wave's head, all m-chunks ----
    #pragma unroll
    for (int c = 0; c < CH; ++c) {
        const int m = c * 64 + ln;
        float l[RR];
        #pragma unroll
        for (int r = 0; r < RR; ++r)
            l[r] = biasb[(size_t)r * NN + m];

        #pragma unroll
        for (int dc = 0; dc < DD; dc += 8) {
            float k8[8];
            #pragma unroll
            for (int i = 0; i < 8; ++i)
                k8[i] = kp[(size_t)(dc + i) * NN + m];
            #pragma unroll
            for (int i = 0; i < 8; ++i) {
                #pragma unroll
                for (int r = 0; r < RR; ++r)
                    l[r] += qb[r * EE + dc + i] * k8[i];
            }
        }

        #pragma unroll
        for (int rp = 0; rp < RR / 2; ++rp) {
            const float e0 = __expf(l[2 * rp]);        // |l| ~ 10 << 88: safe
            const float e1 = __expf(l[2 * rp + 1]);
            S[2 * rp]     += e0;
            S[2 * rp + 1] += e1;
            ep[c][rp] =
                (unsigned)__bfloat16_as_ushort(__float2bfloat16(e0)) |
                ((unsigned)__bfloat16_as_ushort(__float2bfloat16(e1)) << 16);
        }
    }

    // wave-local softmax denominators (no barrier, no LDS)
    float srcp[RR];
    #pragma unroll
    for (int r = 0; r < RR; ++r) {
        float x = S[r];
        #pragma unroll
        for (int off = 32; off; off >>= 1)
            x += __shfl_xor(x, off, 64);
        srcp[r] = __builtin_amdgcn_rcpf(x);
    }

    __syncthreads();                           // sdp ready

    // ---- Phase 2: fold vw, delta, mask over this head's columns ----
    const int doa = drop_or_add[0];
    float A[RR][3];
    #pragma unroll
    for (int r = 0; r < RR; ++r) { A[r][0] = 0.f; A[r][1] = 0.f; A[r][2] = 0.f; }

    const float* vwb = vw + (size_t)(b * HH + h) * 3 * NN;
    #pragma unroll
    for (int c = 0; c < CH; ++c) {
        const int m = c * 64 + ln;
        const float v0 = vwb[m], v1 = vwb[NN + m], v2 = vwb[2 * NN + m];
        #pragma unroll
        for (int r = 0; r < RR; ++r) {
            const unsigned u = ep[c][r >> 1];
            const float e = (r & 1) ? __uint_as_float(u & 0xffff0000u)
                                    : __uint_as_float(u << 16);
            const float mk =
                (doa != 0 && drop_edge_mask[(n0 + r) * NN + m] != 0) ? 0.f : 1.f;
            const float t = e * srcp[r] * mk;
            A[r][0] += t * v0 * sdp[r * 1536 + 3 * m + 0];
            A[r][1] += t * v1 * sdp[r * 1536 + 3 * m + 1];
            A[r][2] += t * v2 * sdp[r * 1536 + 3 * m + 2];
        }
    }

    // ---- Phase 3: wave butterfly + cross-head fold ----
    #pragma unroll
    for (int r = 0; r < RR; ++r) {
        #pragma unroll
        for (int c3 = 0; c3 < 3; ++c3) {
            float x = A[r][c3];
            #pragma unroll
            for (int off = 32; off; off >>= 1)
                x += __shfl_xor(x, off, 64);
            A[r][c3] = x;
        }
    }
    if (ln == 0) {
        #pragma unroll
        for (int r = 0; r < RR; ++r) {
            #pragma unroll
            for (int c3 = 0; c3 < 3; ++c3)
                r3[h][r * 3 + c3] = A[r][c3];
        }
    }
    __syncthreads();

    if (tid < RR * 3) {                        // 12 threads
        float s = 0.f;
        #pragma unroll
        for (int hh = 0; hh < HH; ++hh) s += r3[hh][tid];
        const int r = tid / 3, cc = tid % 3;
        const float bias = (cc == 0) ? bf1[0] : (cc == 1) ? bf2[0] : bf3[0];
        out[(b * NN + n0 + r) * 3 + cc] = s + bias;
    }
}

// ---------------------------------------------------------------------------
extern "C" void kernel_launch(void* const* d_in, const int* in_sizes, int n_in,
                              void* d_out, int out_size, void* d_ws, size_t ws_size,
                              hipStream_t stream)
{
    const float* query          = (const float*)d_in[0];
    const float* attn_bias      = (const float*)d_in[1];
    const float* delta_pos      = (const float*)d_in[2];
    const int*   drop_edge_mask = (const int*)d_in[3];
    const float* Wq  = (const float*)d_in[4];
    const float* bq  = (const float*)d_in[5];
    const float* Wk  = (const float*)d_in[6];
    const float* bk  = (const float*)d_in[7];
    const float* Wv  = (const float*)d_in[8];
    const float* bv  = (const float*)d_in[9];
    const float* Wf1 = (const float*)d_in[10];
    const float* bf1 = (const float*)d_in[11];
    const float* Wf2 = (const float*)d_in[12];
    const float* bf2 = (const float*)d_in[13];
    const float* Wf3 = (const float*)d_in[14];
    const float* bf3 = (const float*)d_in[15];
    const int*   drop_or_add = (const int*)d_in[16];

    float* ws = (float*)d_ws;
    float* Q   = ws;                 // 524288 floats
    float* Kt  = ws + 524288;        // 524288 floats
    float* vw  = ws + 1048576;       // 49152 floats

    proj_kernel<<<dim3(BB * NN / PR, 3), 256, 0, stream>>>(
        query, Wq, bq, Wk, bk, Wv, bv, Wf1, Wf2, Wf3, Q, Kt, vw);
    attn_fused_kernel<<<BB * NN / RR, 512, 0, stream>>>(
        Q, Kt, attn_bias, vw, delta_pos, drop_edge_mask, drop_or_add,
        bf1, bf2, bf3, (float*)d_out);
}

// Round 11
// 64.442 us; speedup vs baseline: 1.2454x; 1.2454x over previous
//
#include <hip/hip_runtime.h>
#include <hip/hip_bf16.h>

#define BB 4
#define NN 512
#define EE 256
#define HH 8
#define DD 32
#define SCALING 0.17677669529663687f  // 32^-0.5
#define PR 8   // rows per proj block
#define RL 8   // rows per logits block (one head per block)

// ---------------------------------------------------------------------------
// Projection, one W per block (blockIdx.y: 0=Q,1=K,2=V).  Q pre-scaled
// [b,n,e]; K transposed Kt[((b*H+h)*D+d)*N+n] (coalesced reads in logits);
// V folded against Wf1/2/3 -> vw[((b*H+h)*3+c)*N+m].  768 blocks.
// ---------------------------------------------------------------------------
__global__ __launch_bounds__(256) void proj_kernel(
    const float* __restrict__ query,
    const float* __restrict__ Wq, const float* __restrict__ bq,
    const float* __restrict__ Wk, const float* __restrict__ bk,
    const float* __restrict__ Wv, const float* __restrict__ bv,
    const float* __restrict__ Wf1, const float* __restrict__ Wf2,
    const float* __restrict__ Wf3,
    float* __restrict__ Q, float* __restrict__ Kt, float* __restrict__ vw)
{
    __shared__ alignas(16) float s[PR][EE];    // 8 KB
    __shared__ alignas(16) float sv[PR][EE];   // 8 KB (V blocks only)
    const int which = blockIdx.y;
    const int row0 = blockIdx.x * PR;
    const int tid = threadIdx.x;               // output column e

    {
        const float4* src = (const float4*)(query + row0 * EE);
        ((float4*)s)[tid]       = src[tid];
        ((float4*)s)[tid + 256] = src[tid + 256];
    }
    __syncthreads();

    const float* W  = (which == 0) ? Wq : (which == 1) ? Wk : Wv;
    const float* bb = (which == 0) ? bq : (which == 1) ? bk : bv;

    float acc[PR];
    #pragma unroll
    for (int r = 0; r < PR; ++r) acc[r] = 0.f;

    const float4* W4 = (const float4*)(W + tid * EE);
    for (int j = 0; j < EE / 4; ++j) {
        const float4 w = W4[j];
        #pragma unroll
        for (int r = 0; r < PR; ++r) {
            const float4 x = *(const float4*)&s[r][4 * j];
            acc[r] += x.x * w.x + x.y * w.y + x.z * w.z + x.w * w.w;
        }
    }
    const float bbv = bb[tid];

    if (which == 0) {
        #pragma unroll
        for (int r = 0; r < PR; ++r)
            Q[(row0 + r) * EE + tid] = (acc[r] + bbv) * SCALING;
    } else if (which == 1) {
        const int h = tid >> 5, d = tid & 31;
        #pragma unroll
        for (int r = 0; r < PR; ++r) {
            const int grow = row0 + r;
            const int b = grow >> 9, n = grow & 511;
            Kt[((size_t)(b * HH + h) * DD + d) * NN + n] = acc[r] + bbv;
        }
    } else {
        #pragma unroll
        for (int r = 0; r < PR; ++r) sv[r][tid] = acc[r] + bbv;
        __syncthreads();
        if (tid < PR * 24) {                   // 192 threads: (r, h, c)
            const int r = tid / 24;
            const int rem = tid % 24;
            const int hh = rem / 3;
            const int c = rem % 3;
            const float* Wf = (c == 0) ? Wf1 : (c == 1) ? Wf2 : Wf3;
            float a = 0.f;
            #pragma unroll
            for (int dd = 0; dd < DD; ++dd)
                a += sv[r][hh * DD + dd] * Wf[hh * DD + dd];
            const int grow = row0 + r;
            const int b = grow >> 9, m = grow & 511;
            vw[((b * HH + hh) * 3 + c) * NN + m] = a;
        }
    }
}

// ---------------------------------------------------------------------------
// Logits: block = (b, 8 rows, ONE head h = blockIdx.y).  Thread = column m.
// K column held in 32 registers (coalesced loads from Kt), reused across 8
// rows -> K L2 traffic halved vs RR=4/HPB=2.  e -> P' (bf16) + per-wave S
// partials.  Barrier-free, LDS-free.  Grid (256, 8) = 2048 blocks.
// ---------------------------------------------------------------------------
__global__ __launch_bounds__(512) void logits_kernel(
    const float* __restrict__ Q, const float* __restrict__ Kt,
    const float* __restrict__ attn_bias,
    __hip_bfloat16* __restrict__ Pp, float* __restrict__ Spart)
{
    const int blk = blockIdx.x;                // 256 blocks in x
    const int b = blk >> 6;
    const int n0 = (blk & 63) * RL;
    const int h = blockIdx.y;
    const int m = threadIdx.x;                 // column m
    const int wv = m >> 6, ln = m & 63;

    const float* kp = Kt + ((size_t)(b * HH + h) * DD) * NN + m;
    float kreg[DD];
    #pragma unroll
    for (int d = 0; d < DD; ++d) kreg[d] = kp[(size_t)d * NN];

    const size_t bias_base = ((size_t)(b * HH + h) * NN + n0) * NN + m;
    const float* qb = Q + (b * NN + n0) * EE + h * DD;      // block-uniform

    #pragma unroll
    for (int r = 0; r < RL; ++r) {
        float l = attn_bias[bias_base + (size_t)r * NN];
        #pragma unroll
        for (int d = 0; d < DD; ++d)
            l += qb[r * EE + d] * kreg[d];
        const float e = __expf(l);             // |l| ~ 10 << 88: safe

        Pp[((size_t)(b * HH + h) * NN + (n0 + r)) * NN + m] =
            __float2bfloat16(e);

        float x = e;
        #pragma unroll
        for (int off = 32; off; off >>= 1)
            x += __shfl_xor(x, off, 64);
        if (ln == 0)
            Spart[((size_t)(b * HH + h) * NN + (n0 + r)) * 8 + wv] = x;
    }
}

// ---------------------------------------------------------------------------
// Contract: per (b,n): fold S partials -> rcpS; A_c = sum_h P'*vw_c*rcpS;
// apply delta/mask (delta staged coalesced through LDS); 3 block reductions.
// ---------------------------------------------------------------------------
__global__ __launch_bounds__(512) void contract_kernel(
    const __hip_bfloat16* __restrict__ Pp, const float* __restrict__ Spart,
    const float* __restrict__ vw, const float* __restrict__ delta_pos,
    const int* __restrict__ drop_edge_mask, const int* __restrict__ drop_or_add,
    const float* __restrict__ bf1, const float* __restrict__ bf2,
    const float* __restrict__ bf3, float* __restrict__ out)
{
    const int blk = blockIdx.x;                // 2048 blocks
    const int b = blk >> 9, n = blk & 511;
    const int m = threadIdx.x;
    const int wv_id = m >> 6, ln = m & 63;

    __shared__ float sred[64];
    __shared__ float srcp[HH];
    __shared__ float r3[3][8];
    __shared__ float sdp[3 * NN];              // 6 KB staged delta row

    // coalesced stage of delta_pos row (1536 contiguous floats)
    {
        const float* dpb = delta_pos + (size_t)(b * NN + n) * NN * 3;
        sdp[m]        = dpb[m];
        sdp[m + 512]  = dpb[m + 512];
        sdp[m + 1024] = dpb[m + 1024];
    }
    if (m < 64)
        sred[m] = Spart[((size_t)(b * HH + (m >> 3)) * NN + n) * 8 + (m & 7)];
    __syncthreads();
    if (m < HH) {
        float s = 0.f;
        #pragma unroll
        for (int w = 0; w < 8; ++w) s += sred[m * 8 + w];
        srcp[m] = __builtin_amdgcn_rcpf(s);
    }
    __syncthreads();

    float A0 = 0.f, A1 = 0.f, A2 = 0.f;
    #pragma unroll
    for (int h = 0; h < HH; ++h) {
        const float p =
            __bfloat162float(Pp[((size_t)(b * HH + h) * NN + n) * NN + m]) *
            srcp[h];
        const float* vwp = vw + (b * HH + h) * 3 * NN + m;
        A0 += p * vwp[0];
        A1 += p * vwp[NN];
        A2 += p * vwp[2 * NN];
    }

    const float mk =
        (drop_or_add[0] != 0 && drop_edge_mask[n * NN + m] != 0) ? 0.f : 1.f;
    float v0 = A0 * sdp[3 * m + 0] * mk;
    float v1 = A1 * sdp[3 * m + 1] * mk;
    float v2 = A2 * sdp[3 * m + 2] * mk;
    #pragma unroll
    for (int off = 32; off; off >>= 1) {
        v0 += __shfl_xor(v0, off, 64);
        v1 += __shfl_xor(v1, off, 64);
        v2 += __shfl_xor(v2, off, 64);
    }
    if (ln == 0) { r3[0][wv_id] = v0; r3[1][wv_id] = v1; r3[2][wv_id] = v2; }
    __syncthreads();

    if (m < 3) {
        float s = 0.f;
        #pragma unroll
        for (int w = 0; w < 8; ++w) s += r3[m][w];
        const float bias = (m == 0) ? bf1[0] : (m == 1) ? bf2[0] : bf3[0];
        out[(b * NN + n) * 3 + m] = s + bias;
    }
}

// ---------------------------------------------------------------------------
extern "C" void kernel_launch(void* const* d_in, const int* in_sizes, int n_in,
                              void* d_out, int out_size, void* d_ws, size_t ws_size,
                              hipStream_t stream)
{
    const float* query          = (const float*)d_in[0];
    const float* attn_bias      = (const float*)d_in[1];
    const float* delta_pos      = (const float*)d_in[2];
    const int*   drop_edge_mask = (const int*)d_in[3];
    const float* Wq  = (const float*)d_in[4];
    const float* bq  = (const float*)d_in[5];
    const float* Wk  = (const float*)d_in[6];
    const float* bk  = (const float*)d_in[7];
    const float* Wv  = (const float*)d_in[8];
    const float* bv  = (const float*)d_in[9];
    const float* Wf1 = (const float*)d_in[10];
    const float* bf1 = (const float*)d_in[11];
    const float* Wf2 = (const float*)d_in[12];
    const float* bf2 = (const float*)d_in[13];
    const float* Wf3 = (const float*)d_in[14];
    const float* bf3 = (const float*)d_in[15];
    const int*   drop_or_add = (const int*)d_in[16];

    float* ws = (float*)d_ws;
    float* Q     = ws;                     // 524288 floats
    float* Kt    = ws + 524288;            // 524288 floats
    float* vw    = ws + 1048576;           // 49152 floats
    float* Spart = ws + 1097728;           // B*H*N*8 = 131072 floats
    __hip_bfloat16* Pp = (__hip_bfloat16*)(ws + 1228800);  // B*H*N*N bf16 = 16.8 MB

    proj_kernel<<<dim3(BB * NN / PR, 3), 256, 0, stream>>>(
        query, Wq, bq, Wk, bk, Wv, bv, Wf1, Wf2, Wf3, Q, Kt, vw);
    logits_kernel<<<dim3(BB * NN / RL, HH), 512, 0, stream>>>(
        Q, Kt, attn_bias, Pp, Spart);
    contract_kernel<<<BB * NN, 512, 0, stream>>>(Pp, Spart, vw, delta_pos,
                                                 drop_edge_mask, drop_or_add,
                                                 bf1, bf2, bf3, (float*)d_out);
}